// Round 6
// baseline (942.347 us; speedup 1.0000x reference)
//
#include <hip/hip_runtime.h>

// Problem dims
#define B_DIM 64
#define IN_CH 16
#define H_DIM 256
#define FDIM  128
#define NF    1001
#define INS0  144      // FDIM + IN_CH
#define TB    7        // timesteps per block in gf_kernel (1001 = 7*143)
#define U     7        // timesteps per pipeline epoch (1001 = 7*143, exact)
#define NEPOCH 143
#define CH    2        // independent batch chains interleaved per wave

// Gate pre-activations are PRE-SCALED so they feed v_exp_f32 (exp2) directly:
//   rows i,f,o:  scale = -log2(e)    -> exp2(arg) = e^{-gate}
//   row  g:      scale = -2*log2(e)  -> exp2(arg) = e^{-2*gate}
#define SC_IFO (-1.44269504088896340736f)
#define SC_G   (-2.88539008177792681472f)

__device__ __forceinline__ float gate_scale(int j) {
    return (j >= 512 && j < 768) ? SC_G : SC_IFO;
}

// ---------------------------------------------------------------------------
// Wave64 sum-reduce via DPP (VALU-rate). Result broadcast via readlane 63.
// ---------------------------------------------------------------------------
template<int CTRL, int ROW_MASK>
__device__ __forceinline__ float dpp_add(float x) {
    int y = __builtin_amdgcn_update_dpp(0, __float_as_int(x), CTRL, ROW_MASK, 0xf, true);
    return x + __int_as_float(y);
}
__device__ __forceinline__ float wave_allreduce(float x) {
    x = dpp_add<0x111, 0xf>(x);   // row_shr:1
    x = dpp_add<0x112, 0xf>(x);   // row_shr:2
    x = dpp_add<0x114, 0xf>(x);   // row_shr:4
    x = dpp_add<0x118, 0xf>(x);   // row_shr:8
    x = dpp_add<0x142, 0xa>(x);   // row_bcast:15 into rows 1,3
    x = dpp_add<0x143, 0xc>(x);   // row_bcast:31 into rows 2,3
    return __int_as_float(__builtin_amdgcn_readlane(__float_as_int(x), 63));
}

// One lane's 4 hidden units for one chain: 5 exp + 2 rcp per unit.
//   A=e^-gi B=e^-2gg D=e^-gf F=e^-go C=e^-2c
//   r1=rcp((1+A)(1+B)(1+D)): si*tg=(1-B)(1+D)r1 ; sf=(1+A)(1+B)r1
//   r2=rcp((1+F)(1+C)):      hr=(1-C)r2
__device__ __forceinline__ float lstm_unit4(const float pre[16], const float whh[16],
                                            const float whr[4], float c4[4], float h)
{
    float m[4];
#pragma unroll
    for (int jj = 0; jj < 4; ++jj) {
        float gi_s = fmaf(h, whh[0*4+jj], pre[0*4+jj]);
        float gf_s = fmaf(h, whh[1*4+jj], pre[1*4+jj]);
        float gg_s = fmaf(h, whh[2*4+jj], pre[2*4+jj]);
        float go_s = fmaf(h, whh[3*4+jj], pre[3*4+jj]);
        float A  = __builtin_amdgcn_exp2f(gi_s);
        float Dv = __builtin_amdgcn_exp2f(gf_s);
        float Bv = __builtin_amdgcn_exp2f(gg_s);
        float Fv = __builtin_amdgcn_exp2f(go_s);
        float a1 = 1.f + A, b1 = 1.f + Bv, d1 = 1.f + Dv, f1 = 1.f + Fv;
        float p1 = a1 * b1;
        float r1 = __builtin_amdgcn_rcpf(p1 * d1);
        float si_tg = (1.f - Bv) * d1 * r1;
        float sf    = p1 * r1;
        float c  = fmaf(sf, c4[jj], si_tg);
        c4[jj] = c;
        float Cv = __builtin_amdgcn_exp2f(SC_G * c);
        float r2 = __builtin_amdgcn_rcpf(f1 * (1.f + Cv));
        float hr = (1.f - Cv) * r2;
        m[jj] = hr * whr[jj];
    }
    return (m[0] + m[1]) + (m[2] + m[3]);
}

// ---------------------------------------------------------------------------
// Gf[t][j] = (sum_k f[t][k] * Wih0[j][k]) * gate_scale(j)   (batch-independent)
// ---------------------------------------------------------------------------
__global__ __launch_bounds__(1024) void gf_kernel(
    const float* __restrict__ f, const float* __restrict__ W,
    float* __restrict__ Gf)
{
    __shared__ float fs[TB][FDIM];
    const int t0 = blockIdx.x * TB;
    const int tid = threadIdx.x;
    for (int i = tid; i < TB * FDIM; i += 1024)
        fs[i >> 7][i & 127] = f[t0 * FDIM + i];
    __syncthreads();

    const int j = tid;
    const float4* w4 = (const float4*)(W + j * INS0);
    float acc[TB];
#pragma unroll
    for (int t = 0; t < TB; ++t) acc[t] = 0.f;
#pragma unroll
    for (int kc = 0; kc < 8; ++kc) {
        float4 a = w4[kc * 4 + 0];
        float4 b = w4[kc * 4 + 1];
        float4 c = w4[kc * 4 + 2];
        float4 d = w4[kc * 4 + 3];
#pragma unroll
        for (int t = 0; t < TB; ++t) {
            const float* fp = &fs[t][kc * 16];
            float s = acc[t];
            s = fmaf(a.x, fp[0], s);  s = fmaf(a.y, fp[1], s);
            s = fmaf(a.z, fp[2], s);  s = fmaf(a.w, fp[3], s);
            s = fmaf(b.x, fp[4], s);  s = fmaf(b.y, fp[5], s);
            s = fmaf(b.z, fp[6], s);  s = fmaf(b.w, fp[7], s);
            s = fmaf(c.x, fp[8], s);  s = fmaf(c.y, fp[9], s);
            s = fmaf(c.z, fp[10], s); s = fmaf(c.w, fp[11], s);
            s = fmaf(d.x, fp[12], s); s = fmaf(d.y, fp[13], s);
            s = fmaf(d.z, fp[14], s); s = fmaf(d.w, fp[15], s);
            acc[t] = s;
        }
    }
    const float sc = gate_scale(j);
#pragma unroll
    for (int t = 0; t < TB; ++t)
        Gf[(size_t)(t0 + t) * 1024 + j] = acc[t] * sc;
}

// ---------------------------------------------------------------------------
// Gxb[b][j] = (sum_k x[b][k]*Wih0[j][128+k] + bih0[j] + bhh0[j]) * gate_scale(j)
// ---------------------------------------------------------------------------
__global__ __launch_bounds__(1024) void gxb_kernel(
    const float* __restrict__ x, const float* __restrict__ W,
    const float* __restrict__ bih, const float* __restrict__ bhh,
    float* __restrict__ Gxb)
{
    const int b = blockIdx.x;
    const int j = threadIdx.x;
    const float* w = W + j * INS0 + FDIM;
    const float* xb = x + b * IN_CH;
    float s = bih[j] + bhh[j];
#pragma unroll
    for (int k = 0; k < IN_CH; ++k) s = fmaf(xb[k], w[k], s);
    Gxb[b * 1024 + j] = s * gate_scale(j);
}

// ---------------------------------------------------------------------------
// Main recurrence, epoch-pipelined, CH=2 chains per wave. grid = 32 blocks
// (batches 2i, 2i+1), 3 waves (wave l = layer l), barrier per epoch (U=7).
// The two chains are independent; their instruction streams interleave on the
// SIMD, filling each other's dependency-latency bubbles. Gf row / whh / whr /
// (layers 1,2) base+wih are shared between chains; only c4[], h, and wave-0's
// Gxb base duplicate.
// ---------------------------------------------------------------------------
__global__ __launch_bounds__(192) void lstm_pipeline(
    const float* __restrict__ Gf, const float* __restrict__ Gxb,
    const float* __restrict__ Whh0, const float* __restrict__ Whr0,
    const float* __restrict__ Wih1, const float* __restrict__ Whh1,
    const float* __restrict__ bih1, const float* __restrict__ bhh1,
    const float* __restrict__ Whr1,
    const float* __restrict__ Wih2, const float* __restrict__ Whh2,
    const float* __restrict__ bih2, const float* __restrict__ bhh2,
    const float* __restrict__ Whr2,
    float* __restrict__ out)
{
    const int b0   = blockIdx.x * CH;     // chains: b0 (A), b0+1 (B)
    const int wave = threadIdx.x >> 6;
    const int lane = threadIdx.x & 63;
    const int jb   = lane * 4;

    __shared__ float hbuf[3][2][CH][8];   // [layer][parity][chain][step]

    float baseA[16], baseB[16];  // wave0: per-chain Gxb; wave1/2: baseA shared
    float wih[16];               // wave1/2: W_ih column * scale (shared)
    float whh[16];               // recurrent column * scale (shared)
    float whr[4];                // projection row slice (shared)

    const float *whh_p, *whr_p;
    if (wave == 0)      { whh_p = Whh0; whr_p = Whr0; }
    else if (wave == 1) { whh_p = Whh1; whr_p = Whr1; }
    else                { whh_p = Whh2; whr_p = Whr2; }

#pragma unroll
    for (int g = 0; g < 4; ++g) {
        const float sc = (g == 2) ? SC_G : SC_IFO;
        float4 w = *(const float4*)(whh_p + g * 256 + jb);
        whh[g*4+0] = w.x * sc; whh[g*4+1] = w.y * sc;
        whh[g*4+2] = w.z * sc; whh[g*4+3] = w.w * sc;
    }
    {
        float4 w = *(const float4*)(whr_p + jb);
        whr[0] = w.x; whr[1] = w.y; whr[2] = w.z; whr[3] = w.w;
    }

    if (wave == 0) {
#pragma unroll
        for (int g = 0; g < 4; ++g) {
            float4 va = *(const float4*)(Gxb + (size_t)b0 * 1024 + g * 256 + jb);
            float4 vb = *(const float4*)(Gxb + (size_t)(b0 + 1) * 1024 + g * 256 + jb);
            baseA[g*4+0] = va.x; baseA[g*4+1] = va.y; baseA[g*4+2] = va.z; baseA[g*4+3] = va.w;
            baseB[g*4+0] = vb.x; baseB[g*4+1] = vb.y; baseB[g*4+2] = vb.z; baseB[g*4+3] = vb.w;
            wih[g*4+0] = 0.f; wih[g*4+1] = 0.f; wih[g*4+2] = 0.f; wih[g*4+3] = 0.f;
        }
    } else {
        const float* bi = (wave == 1) ? bih1 : bih2;
        const float* bh = (wave == 1) ? bhh1 : bhh2;
        const float* wi = (wave == 1) ? Wih1 : Wih2;
#pragma unroll
        for (int g = 0; g < 4; ++g) {
            const float sc = (g == 2) ? SC_G : SC_IFO;
            float4 v1 = *(const float4*)(bi + g * 256 + jb);
            float4 v2 = *(const float4*)(bh + g * 256 + jb);
            float4 v3 = *(const float4*)(wi + g * 256 + jb);
            baseA[g*4+0] = (v1.x + v2.x) * sc; baseA[g*4+1] = (v1.y + v2.y) * sc;
            baseA[g*4+2] = (v1.z + v2.z) * sc; baseA[g*4+3] = (v1.w + v2.w) * sc;
            baseB[g*4+0] = baseA[g*4+0]; baseB[g*4+1] = baseA[g*4+1];
            baseB[g*4+2] = baseA[g*4+2]; baseB[g*4+3] = baseA[g*4+3];
            wih[g*4+0] = v3.x * sc; wih[g*4+1] = v3.y * sc;
            wih[g*4+2] = v3.z * sc; wih[g*4+3] = v3.w * sc;
        }
    }

    float c4A[4] = {0.f, 0.f, 0.f, 0.f};
    float c4B[4] = {0.f, 0.f, 0.f, 0.f};
    float hA = 0.f, hB = 0.f;

    for (int e = 0; e < NEPOCH + 2; ++e) {
        __syncthreads();
        const int te = e - wave;
        if (te < 0 || te >= NEPOCH) continue;   // all waves still hit barrier

        float hinA[8], hinB[8];
        if (wave > 0) {
            const int par = (e - 1) & 1;
            float4 a0 = *(const float4*)&hbuf[wave - 1][par][0][0];
            float4 a1 = *(const float4*)&hbuf[wave - 1][par][0][4];
            float4 b0v = *(const float4*)&hbuf[wave - 1][par][1][0];
            float4 b1v = *(const float4*)&hbuf[wave - 1][par][1][4];
            hinA[0]=a0.x; hinA[1]=a0.y; hinA[2]=a0.z; hinA[3]=a0.w;
            hinA[4]=a1.x; hinA[5]=a1.y; hinA[6]=a1.z; hinA[7]=a1.w;
            hinB[0]=b0v.x; hinB[1]=b0v.y; hinB[2]=b0v.z; hinB[3]=b0v.w;
            hinB[4]=b1v.x; hinB[5]=b1v.y; hinB[6]=b1v.z; hinB[7]=b1v.w;
        }

        const int s_base = te * U;
#pragma unroll
        for (int u = 0; u < U; ++u) {
            float preA[16], preB[16];
            if (wave == 0) {
                const float* p = Gf + (size_t)(s_base + u) * 1024;
#pragma unroll
                for (int g = 0; g < 4; ++g) {
                    float4 v = *(const float4*)(p + g * 256 + jb);
                    preA[g*4+0] = v.x + baseA[g*4+0]; preA[g*4+1] = v.y + baseA[g*4+1];
                    preA[g*4+2] = v.z + baseA[g*4+2]; preA[g*4+3] = v.w + baseA[g*4+3];
                    preB[g*4+0] = v.x + baseB[g*4+0]; preB[g*4+1] = v.y + baseB[g*4+1];
                    preB[g*4+2] = v.z + baseB[g*4+2]; preB[g*4+3] = v.w + baseB[g*4+3];
                }
            } else {
                const float ha = hinA[u], hb = hinB[u];
#pragma unroll
                for (int i = 0; i < 16; ++i) {
                    preA[i] = fmaf(ha, wih[i], baseA[i]);
                    preB[i] = fmaf(hb, wih[i], baseB[i]);
                }
            }

            float contribA = lstm_unit4(preA, whh, whr, c4A, hA);
            float contribB = lstm_unit4(preB, whh, whr, c4B, hB);
            float totA = wave_allreduce(contribA);
            float totB = wave_allreduce(contribB);
            hA = totA; hB = totB;
            if (lane == 0) {
                hbuf[wave][e & 1][0][u] = totA;
                hbuf[wave][e & 1][1][u] = totB;
            }
            if (wave == 2 && lane == 0) {
                out[(size_t)b0 * NF + s_base + u]       = totA;
                out[(size_t)(b0 + 1) * NF + s_base + u] = totB;
            }
        }
    }
}

// ---------------------------------------------------------------------------
extern "C" void kernel_launch(void* const* d_in, const int* in_sizes, int n_in,
                              void* d_out, int out_size, void* d_ws, size_t ws_size,
                              hipStream_t stream)
{
    const float* x    = (const float*)d_in[0];
    const float* f    = (const float*)d_in[1];
    const float* Wih0 = (const float*)d_in[2];
    const float* Whh0 = (const float*)d_in[3];
    const float* bih0 = (const float*)d_in[4];
    const float* bhh0 = (const float*)d_in[5];
    const float* Whr0 = (const float*)d_in[6];
    const float* Wih1 = (const float*)d_in[7];
    const float* Whh1 = (const float*)d_in[8];
    const float* bih1 = (const float*)d_in[9];
    const float* bhh1 = (const float*)d_in[10];
    const float* Whr1 = (const float*)d_in[11];
    const float* Wih2 = (const float*)d_in[12];
    const float* Whh2 = (const float*)d_in[13];
    const float* bih2 = (const float*)d_in[14];
    const float* bhh2 = (const float*)d_in[15];
    const float* Whr2 = (const float*)d_in[16];
    float* out = (float*)d_out;

    float* Gf  = (float*)d_ws;                       // NF * 1024 floats (4.1 MB)
    float* Gxb = Gf + (size_t)NF * 1024;             // 64 * 1024 floats

    gf_kernel<<<143, 1024, 0, stream>>>(f, Wih0, Gf);
    gxb_kernel<<<64, 1024, 0, stream>>>(x, Wih0, bih0, bhh0, Gxb);
    lstm_pipeline<<<B_DIM / CH, 192, 0, stream>>>(Gf, Gxb, Whh0, Whr0,
                                                  Wih1, Whh1, bih1, bhh1, Whr1,
                                                  Wih2, Whh2, bih2, bhh2, Whr2,
                                                  out);
}

// Round 7
// 876.049 us; speedup vs baseline: 1.0757x; 1.0757x over previous
//
#include <hip/hip_runtime.h>

// Problem dims
#define B_DIM 64
#define IN_CH 16
#define H_DIM 256
#define FDIM  128
#define NF    1001
#define INS0  144      // FDIM + IN_CH
#define TB    7        // timesteps per block in gf_kernel (1001 = 7*143)
#define U     7        // timesteps per pipeline epoch (1001 = 7*143, exact)
#define NEPOCH 143
#define CH    2        // independent batch chains, packed .x/.y in v2f

// Gate pre-activations are PRE-SCALED so they feed v_exp_f32 (exp2) directly:
//   rows i,f,o:  scale = -log2(e)    -> exp2(arg) = e^{-gate}
//   row  g:      scale = -2*log2(e)  -> exp2(arg) = e^{-2*gate}
#define SC_IFO (-1.44269504088896340736f)
#define SC_G   (-2.88539008177792681472f)

typedef float v2f __attribute__((ext_vector_type(2)));

__device__ __forceinline__ v2f v2mk(float a, float b) { v2f r; r.x = a; r.y = b; return r; }
__device__ __forceinline__ v2f vsplat(float a)        { v2f r; r.x = a; r.y = a; return r; }
__device__ __forceinline__ v2f vexp2(v2f a) {
    return v2mk(__builtin_amdgcn_exp2f(a.x), __builtin_amdgcn_exp2f(a.y));
}
__device__ __forceinline__ v2f vrcp(v2f a) {
    return v2mk(__builtin_amdgcn_rcpf(a.x), __builtin_amdgcn_rcpf(a.y));
}
__device__ __forceinline__ v2f vfma(v2f a, v2f b, v2f c) {
    return __builtin_elementwise_fma(a, b, c);
}

__device__ __forceinline__ float gate_scale(int j) {
    return (j >= 512 && j < 768) ? SC_G : SC_IFO;
}

// ---------------------------------------------------------------------------
// Wave64 sum-reduce via DPP (VALU-rate). Result broadcast via readlane 63.
// ---------------------------------------------------------------------------
template<int CTRL, int ROW_MASK>
__device__ __forceinline__ float dpp_add(float x) {
    int y = __builtin_amdgcn_update_dpp(0, __float_as_int(x), CTRL, ROW_MASK, 0xf, true);
    return x + __int_as_float(y);
}
__device__ __forceinline__ float wave_allreduce(float x) {
    x = dpp_add<0x111, 0xf>(x);   // row_shr:1
    x = dpp_add<0x112, 0xf>(x);   // row_shr:2
    x = dpp_add<0x114, 0xf>(x);   // row_shr:4
    x = dpp_add<0x118, 0xf>(x);   // row_shr:8
    x = dpp_add<0x142, 0xa>(x);   // row_bcast:15 into rows 1,3
    x = dpp_add<0x143, 0xc>(x);   // row_bcast:31 into rows 2,3
    return __int_as_float(__builtin_amdgcn_readlane(__float_as_int(x), 63));
}

// Both chains' 4 hidden units, packed: 5 exp + 2 rcp per unit per chain, all
// non-trans math as packed (v_pk_*) ops so the two chains structurally
// interleave in one instruction stream.
__device__ __forceinline__ v2f lstm_unit4_pair(const v2f pre[16], const v2f whh2[16],
                                               const v2f whr2[4], v2f c4[4], v2f h2)
{
    const v2f one = vsplat(1.f);
    v2f acc = vsplat(0.f);
#pragma unroll
    for (int jj = 0; jj < 4; ++jj) {
        v2f gi = vfma(h2, whh2[0*4+jj], pre[0*4+jj]);
        v2f gf = vfma(h2, whh2[1*4+jj], pre[1*4+jj]);
        v2f gg = vfma(h2, whh2[2*4+jj], pre[2*4+jj]);
        v2f go = vfma(h2, whh2[3*4+jj], pre[3*4+jj]);
        v2f A  = vexp2(gi);            // e^-gi
        v2f Dv = vexp2(gf);            // e^-gf
        v2f Bv = vexp2(gg);            // e^-2gg
        v2f Fv = vexp2(go);            // e^-go
        v2f a1 = one + A, b1 = one + Bv, d1 = one + Dv, f1 = one + Fv;
        v2f p1 = a1 * b1;
        v2f r1 = vrcp(p1 * d1);
        v2f si_tg = (one - Bv) * d1 * r1;   // sigmoid(gi)*tanh(gg)
        v2f sf    = p1 * r1;                // sigmoid(gf)
        v2f c = vfma(sf, c4[jj], si_tg);
        c4[jj] = c;
        v2f Cv = vexp2(vsplat(SC_G) * c);   // e^-2c
        v2f r2 = vrcp(f1 * (one + Cv));
        v2f hr = (one - Cv) * r2;           // sigmoid(go)*tanh(c)
        acc = vfma(hr, whr2[jj], acc);
    }
    return acc;
}

// ---------------------------------------------------------------------------
// Gf[t][j] = (sum_k f[t][k] * Wih0[j][k]) * gate_scale(j)   (batch-independent)
// ---------------------------------------------------------------------------
__global__ __launch_bounds__(1024) void gf_kernel(
    const float* __restrict__ f, const float* __restrict__ W,
    float* __restrict__ Gf)
{
    __shared__ float fs[TB][FDIM];
    const int t0 = blockIdx.x * TB;
    const int tid = threadIdx.x;
    for (int i = tid; i < TB * FDIM; i += 1024)
        fs[i >> 7][i & 127] = f[t0 * FDIM + i];
    __syncthreads();

    const int j = tid;
    const float4* w4 = (const float4*)(W + j * INS0);
    float acc[TB];
#pragma unroll
    for (int t = 0; t < TB; ++t) acc[t] = 0.f;
#pragma unroll
    for (int kc = 0; kc < 8; ++kc) {
        float4 a = w4[kc * 4 + 0];
        float4 b = w4[kc * 4 + 1];
        float4 c = w4[kc * 4 + 2];
        float4 d = w4[kc * 4 + 3];
#pragma unroll
        for (int t = 0; t < TB; ++t) {
            const float* fp = &fs[t][kc * 16];
            float s = acc[t];
            s = fmaf(a.x, fp[0], s);  s = fmaf(a.y, fp[1], s);
            s = fmaf(a.z, fp[2], s);  s = fmaf(a.w, fp[3], s);
            s = fmaf(b.x, fp[4], s);  s = fmaf(b.y, fp[5], s);
            s = fmaf(b.z, fp[6], s);  s = fmaf(b.w, fp[7], s);
            s = fmaf(c.x, fp[8], s);  s = fmaf(c.y, fp[9], s);
            s = fmaf(c.z, fp[10], s); s = fmaf(c.w, fp[11], s);
            s = fmaf(d.x, fp[12], s); s = fmaf(d.y, fp[13], s);
            s = fmaf(d.z, fp[14], s); s = fmaf(d.w, fp[15], s);
            acc[t] = s;
        }
    }
    const float sc = gate_scale(j);
#pragma unroll
    for (int t = 0; t < TB; ++t)
        Gf[(size_t)(t0 + t) * 1024 + j] = acc[t] * sc;
}

// ---------------------------------------------------------------------------
// Gxb[b][j] = (sum_k x[b][k]*Wih0[j][128+k] + bih0[j] + bhh0[j]) * gate_scale(j)
// ---------------------------------------------------------------------------
__global__ __launch_bounds__(1024) void gxb_kernel(
    const float* __restrict__ x, const float* __restrict__ W,
    const float* __restrict__ bih, const float* __restrict__ bhh,
    float* __restrict__ Gxb)
{
    const int b = blockIdx.x;
    const int j = threadIdx.x;
    const float* w = W + j * INS0 + FDIM;
    const float* xb = x + b * IN_CH;
    float s = bih[j] + bhh[j];
#pragma unroll
    for (int k = 0; k < IN_CH; ++k) s = fmaf(xb[k], w[k], s);
    Gxb[b * 1024 + j] = s * gate_scale(j);
}

// ---------------------------------------------------------------------------
// Main recurrence, epoch-pipelined, CH=2 chains PACKED per lane (v2f .x/.y).
// grid = 32 blocks (batches 2i, 2i+1), 3 waves (wave l = layer l), one
// barrier per U=7-step epoch. __launch_bounds__(192,1) lifts the VGPR cap so
// the scheduler cannot pressure-serialize the chains (round-6 failure mode).
// ---------------------------------------------------------------------------
__global__ __launch_bounds__(192, 1) void lstm_pipeline(
    const float* __restrict__ Gf, const float* __restrict__ Gxb,
    const float* __restrict__ Whh0, const float* __restrict__ Whr0,
    const float* __restrict__ Wih1, const float* __restrict__ Whh1,
    const float* __restrict__ bih1, const float* __restrict__ bhh1,
    const float* __restrict__ Whr1,
    const float* __restrict__ Wih2, const float* __restrict__ Whh2,
    const float* __restrict__ bih2, const float* __restrict__ bhh2,
    const float* __restrict__ Whr2,
    float* __restrict__ out)
{
    const int b0   = blockIdx.x * CH;     // chains: b0 (.x), b0+1 (.y)
    const int wave = threadIdx.x >> 6;
    const int lane = threadIdx.x & 63;
    const int jb   = lane * 4;

    __shared__ float hbuf[3][2][CH][8];   // [layer][parity][chain][step]

    v2f base2[16];   // wave0: per-chain Gxb; wave1/2: same in both halves
    v2f wih2[16];    // W_ih column * scale (splat)
    v2f whh2[16];    // recurrent column * scale (splat)
    v2f whr2[4];     // projection row slice (splat)

    const float *whh_p, *whr_p;
    if (wave == 0)      { whh_p = Whh0; whr_p = Whr0; }
    else if (wave == 1) { whh_p = Whh1; whr_p = Whr1; }
    else                { whh_p = Whh2; whr_p = Whr2; }

#pragma unroll
    for (int g = 0; g < 4; ++g) {
        const float sc = (g == 2) ? SC_G : SC_IFO;
        float4 w = *(const float4*)(whh_p + g * 256 + jb);
        whh2[g*4+0] = vsplat(w.x * sc); whh2[g*4+1] = vsplat(w.y * sc);
        whh2[g*4+2] = vsplat(w.z * sc); whh2[g*4+3] = vsplat(w.w * sc);
    }
    {
        float4 w = *(const float4*)(whr_p + jb);
        whr2[0] = vsplat(w.x); whr2[1] = vsplat(w.y);
        whr2[2] = vsplat(w.z); whr2[3] = vsplat(w.w);
    }

    if (wave == 0) {
#pragma unroll
        for (int g = 0; g < 4; ++g) {
            float4 va = *(const float4*)(Gxb + (size_t)b0 * 1024 + g * 256 + jb);
            float4 vb = *(const float4*)(Gxb + (size_t)(b0 + 1) * 1024 + g * 256 + jb);
            base2[g*4+0] = v2mk(va.x, vb.x); base2[g*4+1] = v2mk(va.y, vb.y);
            base2[g*4+2] = v2mk(va.z, vb.z); base2[g*4+3] = v2mk(va.w, vb.w);
            wih2[g*4+0] = vsplat(0.f); wih2[g*4+1] = vsplat(0.f);
            wih2[g*4+2] = vsplat(0.f); wih2[g*4+3] = vsplat(0.f);
        }
    } else {
        const float* bi = (wave == 1) ? bih1 : bih2;
        const float* bh = (wave == 1) ? bhh1 : bhh2;
        const float* wi = (wave == 1) ? Wih1 : Wih2;
#pragma unroll
        for (int g = 0; g < 4; ++g) {
            const float sc = (g == 2) ? SC_G : SC_IFO;
            float4 v1 = *(const float4*)(bi + g * 256 + jb);
            float4 v2_ = *(const float4*)(bh + g * 256 + jb);
            float4 v3 = *(const float4*)(wi + g * 256 + jb);
            base2[g*4+0] = vsplat((v1.x + v2_.x) * sc);
            base2[g*4+1] = vsplat((v1.y + v2_.y) * sc);
            base2[g*4+2] = vsplat((v1.z + v2_.z) * sc);
            base2[g*4+3] = vsplat((v1.w + v2_.w) * sc);
            wih2[g*4+0] = vsplat(v3.x * sc); wih2[g*4+1] = vsplat(v3.y * sc);
            wih2[g*4+2] = vsplat(v3.z * sc); wih2[g*4+3] = vsplat(v3.w * sc);
        }
    }

    v2f c4[4] = {vsplat(0.f), vsplat(0.f), vsplat(0.f), vsplat(0.f)};
    v2f h2 = vsplat(0.f);

    for (int e = 0; e < NEPOCH + 2; ++e) {
        __syncthreads();
        const int te = e - wave;
        if (te < 0 || te >= NEPOCH) continue;   // all waves still hit barrier

        v2f hin2[8];
        if (wave > 0) {
            const int par = (e - 1) & 1;
            float4 a0 = *(const float4*)&hbuf[wave - 1][par][0][0];
            float4 a1 = *(const float4*)&hbuf[wave - 1][par][0][4];
            float4 bb0 = *(const float4*)&hbuf[wave - 1][par][1][0];
            float4 bb1 = *(const float4*)&hbuf[wave - 1][par][1][4];
            hin2[0] = v2mk(a0.x, bb0.x); hin2[1] = v2mk(a0.y, bb0.y);
            hin2[2] = v2mk(a0.z, bb0.z); hin2[3] = v2mk(a0.w, bb0.w);
            hin2[4] = v2mk(a1.x, bb1.x); hin2[5] = v2mk(a1.y, bb1.y);
            hin2[6] = v2mk(a1.z, bb1.z); hin2[7] = v2mk(a1.w, bb1.w);
        }

        const int s_base = te * U;
#pragma unroll
        for (int u = 0; u < U; ++u) {
            v2f pre[16];
            if (wave == 0) {
                const float* p = Gf + (size_t)(s_base + u) * 1024;
#pragma unroll
                for (int g = 0; g < 4; ++g) {
                    float4 v = *(const float4*)(p + g * 256 + jb);
                    pre[g*4+0] = vsplat(v.x) + base2[g*4+0];
                    pre[g*4+1] = vsplat(v.y) + base2[g*4+1];
                    pre[g*4+2] = vsplat(v.z) + base2[g*4+2];
                    pre[g*4+3] = vsplat(v.w) + base2[g*4+3];
                }
            } else {
                const v2f hu = hin2[u];
#pragma unroll
                for (int i = 0; i < 16; ++i)
                    pre[i] = vfma(hu, wih2[i], base2[i]);
            }

            v2f contrib = lstm_unit4_pair(pre, whh2, whr2, c4, h2);
            float totA = wave_allreduce(contrib.x);
            float totB = wave_allreduce(contrib.y);
            h2 = v2mk(totA, totB);
            if (lane == 0) {
                hbuf[wave][e & 1][0][u] = totA;
                hbuf[wave][e & 1][1][u] = totB;
            }
            if (wave == 2 && lane == 0) {
                out[(size_t)b0 * NF + s_base + u]       = totA;
                out[(size_t)(b0 + 1) * NF + s_base + u] = totB;
            }
        }
    }
}

// ---------------------------------------------------------------------------
extern "C" void kernel_launch(void* const* d_in, const int* in_sizes, int n_in,
                              void* d_out, int out_size, void* d_ws, size_t ws_size,
                              hipStream_t stream)
{
    const float* x    = (const float*)d_in[0];
    const float* f    = (const float*)d_in[1];
    const float* Wih0 = (const float*)d_in[2];
    const float* Whh0 = (const float*)d_in[3];
    const float* bih0 = (const float*)d_in[4];
    const float* bhh0 = (const float*)d_in[5];
    const float* Whr0 = (const float*)d_in[6];
    const float* Wih1 = (const float*)d_in[7];
    const float* Whh1 = (const float*)d_in[8];
    const float* bih1 = (const float*)d_in[9];
    const float* bhh1 = (const float*)d_in[10];
    const float* Whr1 = (const float*)d_in[11];
    const float* Wih2 = (const float*)d_in[12];
    const float* Whh2 = (const float*)d_in[13];
    const float* bih2 = (const float*)d_in[14];
    const float* bhh2 = (const float*)d_in[15];
    const float* Whr2 = (const float*)d_in[16];
    float* out = (float*)d_out;

    float* Gf  = (float*)d_ws;                       // NF * 1024 floats (4.1 MB)
    float* Gxb = Gf + (size_t)NF * 1024;             // 64 * 1024 floats

    gf_kernel<<<143, 1024, 0, stream>>>(f, Wih0, Gf);
    gxb_kernel<<<64, 1024, 0, stream>>>(x, Wih0, bih0, bhh0, Gxb);
    lstm_pipeline<<<B_DIM / CH, 192, 0, stream>>>(Gf, Gxb, Whh0, Whr0,
                                                  Wih1, Whh1, bih1, bhh1, Whr1,
                                                  Wih2, Whh2, bih2, bhh2, Whr2,
                                                  out);
}

// Round 8
// 544.043 us; speedup vs baseline: 1.7321x; 1.6103x over previous
//
#include <hip/hip_runtime.h>

// Problem dims
#define B_DIM 64
#define IN_CH 16
#define H_DIM 256
#define FDIM  128
#define NF    1001
#define INS0  144      // FDIM + IN_CH
#define TB    7        // timesteps per block in gf_kernel (1001 = 7*143)
#define NEP   144      // 144 epochs x 7 = 1008 steps (covers k=0..1007)

// Gate pre-activations are PRE-SCALED so they feed v_exp_f32 (exp2) directly:
//   rows i,f,o:  scale = -log2(e)    -> exp2(arg) = e^{-gate}
//   row  g:      scale = -2*log2(e)  -> exp2(arg) = e^{-2*gate}
#define SC_IFO (-1.44269504088896340736f)
#define SC_G   (-2.88539008177792681472f)

__device__ __forceinline__ float gate_scale(int j) {
    return (j >= 512 && j < 768) ? SC_G : SC_IFO;
}
__device__ __forceinline__ float gsc(int g) { return (g == 2) ? SC_G : SC_IFO; }

// ---------------------------------------------------------------------------
// Wave64 sum-reduce via DPP; full sum lands in lane 63 (no readlane needed —
// lane 63 is the LDS writer).
// ---------------------------------------------------------------------------
template<int CTRL, int ROW_MASK>
__device__ __forceinline__ float dpp_add(float x) {
    int y = __builtin_amdgcn_update_dpp(0, __float_as_int(x), CTRL, ROW_MASK, 0xf, true);
    return x + __int_as_float(y);
}
__device__ __forceinline__ float reduce63(float x) {
    x = dpp_add<0x111, 0xf>(x);   // row_shr:1
    x = dpp_add<0x112, 0xf>(x);   // row_shr:2
    x = dpp_add<0x114, 0xf>(x);   // row_shr:4
    x = dpp_add<0x118, 0xf>(x);   // row_shr:8
    x = dpp_add<0x142, 0xa>(x);   // row_bcast:15 into rows 1,3
    x = dpp_add<0x143, 0xc>(x);   // row_bcast:31 into rows 2,3
    return x;                      // lane 63 holds the 64-lane sum
}

// ---------------------------------------------------------------------------
// Gf[t][j] = (sum_k f[t][k] * Wih0[j][k]) * gate_scale(j)   (batch-independent)
// ---------------------------------------------------------------------------
__global__ __launch_bounds__(1024) void gf_kernel(
    const float* __restrict__ f, const float* __restrict__ W,
    float* __restrict__ Gf)
{
    __shared__ float fs[TB][FDIM];
    const int t0 = blockIdx.x * TB;
    const int tid = threadIdx.x;
    for (int i = tid; i < TB * FDIM; i += 1024)
        fs[i >> 7][i & 127] = f[t0 * FDIM + i];
    __syncthreads();

    const int j = tid;
    const float4* w4 = (const float4*)(W + j * INS0);
    float acc[TB];
#pragma unroll
    for (int t = 0; t < TB; ++t) acc[t] = 0.f;
#pragma unroll
    for (int kc = 0; kc < 8; ++kc) {
        float4 a = w4[kc * 4 + 0];
        float4 b = w4[kc * 4 + 1];
        float4 c = w4[kc * 4 + 2];
        float4 d = w4[kc * 4 + 3];
#pragma unroll
        for (int t = 0; t < TB; ++t) {
            const float* fp = &fs[t][kc * 16];
            float s = acc[t];
            s = fmaf(a.x, fp[0], s);  s = fmaf(a.y, fp[1], s);
            s = fmaf(a.z, fp[2], s);  s = fmaf(a.w, fp[3], s);
            s = fmaf(b.x, fp[4], s);  s = fmaf(b.y, fp[5], s);
            s = fmaf(b.z, fp[6], s);  s = fmaf(b.w, fp[7], s);
            s = fmaf(c.x, fp[8], s);  s = fmaf(c.y, fp[9], s);
            s = fmaf(c.z, fp[10], s); s = fmaf(c.w, fp[11], s);
            s = fmaf(d.x, fp[12], s); s = fmaf(d.y, fp[13], s);
            s = fmaf(d.z, fp[14], s); s = fmaf(d.w, fp[15], s);
            acc[t] = s;
        }
    }
    const float sc = gate_scale(j);
#pragma unroll
    for (int t = 0; t < TB; ++t)
        Gf[(size_t)(t0 + t) * 1024 + j] = acc[t] * sc;
}

// ---------------------------------------------------------------------------
// Gxb[b][j] = (sum_k x[b][k]*Wih0[j][128+k] + bih0[j] + bhh0[j]) * gate_scale(j)
// ---------------------------------------------------------------------------
__global__ __launch_bounds__(1024) void gxb_kernel(
    const float* __restrict__ x, const float* __restrict__ W,
    const float* __restrict__ bih, const float* __restrict__ bhh,
    float* __restrict__ Gxb)
{
    const int b = blockIdx.x;
    const int j = threadIdx.x;
    const float* w = W + j * INS0 + FDIM;
    const float* xb = x + b * IN_CH;
    float s = bih[j] + bhh[j];
#pragma unroll
    for (int k = 0; k < IN_CH; ++k) s = fmaf(xb[k], w[k], s);
    Gxb[b * 1024 + j] = s * gate_scale(j);
}

// ---------------------------------------------------------------------------
// Gf gate quad for unit j0 at timestep t: (i,f,g,o) pre-scaled.
// ---------------------------------------------------------------------------
__device__ __forceinline__ float4 ldgate(const float* __restrict__ Gf, int t, int j0) {
    const float* p = Gf + (size_t)t * 1024 + j0;
    float4 r; r.x = p[0]; r.y = p[256]; r.z = p[512]; r.w = p[768];
    return r;
}

// ---------------------------------------------------------------------------
// One recurrent step for one wave (1 hidden unit per lane).
// Reads own-group partials (h_{t-1}) and upstream partials (hin) from LDS,
// computes the unit, DPP-reduces the projection partial, writes it to LDS.
// Returns h (own layer's previous output) for the output-collection wave.
// ---------------------------------------------------------------------------
__device__ __forceinline__ float step_fn(
    int k, float4 gv, int lay, int lane, int q,
    const float whh[4], const float wih[4], const float base[4], float whr0,
    float& c, float4 (*part4)[2])
{
    const int pr = (k - 1) & 1;
    float4 own = part4[lay][pr];
    float h = (own.x + own.y) + (own.z + own.w);
    const bool active = (k >= lay) && (k < NF + lay);
    if (active) {
        float pre0, pre1, pre2, pre3;
        if (lay == 0) {
            pre0 = gv.x + base[0]; pre1 = gv.y + base[1];
            pre2 = gv.z + base[2]; pre3 = gv.w + base[3];
        } else {
            float4 up = part4[lay - 1][pr];
            float hin = (up.x + up.y) + (up.z + up.w);
            pre0 = fmaf(hin, wih[0], base[0]);
            pre1 = fmaf(hin, wih[1], base[1]);
            pre2 = fmaf(hin, wih[2], base[2]);
            pre3 = fmaf(hin, wih[3], base[3]);
        }
        float gi = fmaf(h, whh[0], pre0);
        float gf_ = fmaf(h, whh[1], pre1);
        float gg = fmaf(h, whh[2], pre2);
        float go = fmaf(h, whh[3], pre3);
        float A  = __builtin_amdgcn_exp2f(gi);    // e^-gi
        float Dv = __builtin_amdgcn_exp2f(gf_);   // e^-gf
        float Bv = __builtin_amdgcn_exp2f(gg);    // e^-2gg
        float Fv = __builtin_amdgcn_exp2f(go);    // e^-go
        float a1 = 1.f + A, b1 = 1.f + Bv, d1 = 1.f + Dv, f1 = 1.f + Fv;
        float p1 = a1 * b1;
        float r1 = __builtin_amdgcn_rcpf(p1 * d1);
        float si_tg = (1.f - Bv) * d1 * r1;       // sigmoid(gi)*tanh(gg)
        float sf    = p1 * r1;                    // sigmoid(gf)
        c = fmaf(sf, c, si_tg);
        float Cv = __builtin_amdgcn_exp2f(SC_G * c);  // e^-2c
        float r2 = __builtin_amdgcn_rcpf(f1 * (1.f + Cv));
        float hr = (1.f - Cv) * r2;               // sigmoid(go)*tanh(c)
        float m = reduce63(hr * whr0);
        if (lane == 63) ((float*)&part4[lay][k & 1])[q] = m;
    }
    return h;
}

// ---------------------------------------------------------------------------
// Main recurrence. grid = 64 (block = batch), 768 threads = 12 waves:
// lay = wid%3 (SIMD-balanced: each SIMD hosts one wave of each layer),
// q = wid/3; each lane owns unit j0 = q*64+lane. Per-step __syncthreads;
// h assembled per wave from 4 LDS quarter-partials (one b128 broadcast read).
// Gf rows register-prefetched 7 steps ahead (vmcnt drain once/epoch);
// outputs buffered 7-deep in regs, stored once per epoch.
// ---------------------------------------------------------------------------
__global__ __launch_bounds__(768, 3) void lstm_pipeline(
    const float* __restrict__ Gf, const float* __restrict__ Gxb,
    const float* __restrict__ Whh0, const float* __restrict__ Whr0,
    const float* __restrict__ Wih1, const float* __restrict__ Whh1,
    const float* __restrict__ bih1, const float* __restrict__ bhh1,
    const float* __restrict__ Whr1,
    const float* __restrict__ Wih2, const float* __restrict__ Whh2,
    const float* __restrict__ bih2, const float* __restrict__ bhh2,
    const float* __restrict__ Whr2,
    float* __restrict__ out)
{
    const int b    = blockIdx.x;
    const int wid  = threadIdx.x >> 6;   // 0..11
    const int lane = threadIdx.x & 63;
    const int lay  = wid % 3;            // layer, one per SIMD slot
    const int q    = wid / 3;            // quarter 0..3
    const int j0   = q * 64 + lane;      // hidden unit owned by this lane

    __shared__ float4 part4[3][2];       // [layer][parity]: 4 quarter-partials
    if (threadIdx.x < 24) ((float*)part4)[threadIdx.x] = 0.f;

    const float *whh_p, *whr_p, *wih_p = nullptr, *bi_p = nullptr, *bh_p = nullptr;
    if (lay == 0)      { whh_p = Whh0; whr_p = Whr0; }
    else if (lay == 1) { whh_p = Whh1; whr_p = Whr1; wih_p = Wih1; bi_p = bih1; bh_p = bhh1; }
    else               { whh_p = Whh2; whr_p = Whr2; wih_p = Wih2; bi_p = bih2; bh_p = bhh2; }

    float whh[4], base[4], wih[4];
#pragma unroll
    for (int g = 0; g < 4; ++g)
        whh[g] = whh_p[g * 256 + j0] * gsc(g);
    const float whr0 = whr_p[j0];
    if (lay == 0) {
#pragma unroll
        for (int g = 0; g < 4; ++g) {
            base[g] = Gxb[(size_t)b * 1024 + g * 256 + j0];  // pre-scaled
            wih[g] = 0.f;
        }
    } else {
#pragma unroll
        for (int g = 0; g < 4; ++g) {
            base[g] = (bi_p[g * 256 + j0] + bh_p[g * 256 + j0]) * gsc(g);
            wih[g] = wih_p[g * 256 + j0] * gsc(g);
        }
    }

    // Gf prefetch (layer-0 waves): current epoch u0..u6, next epoch n0..n6.
    float4 u0{}, u1{}, u2{}, u3{}, u4{}, u5{}, u6{};
    float4 n0{}, n1{}, n2{}, n3{}, n4{}, n5{}, n6{};
    if (lay == 0) {
        n0 = ldgate(Gf, 0, j0); n1 = ldgate(Gf, 1, j0); n2 = ldgate(Gf, 2, j0);
        n3 = ldgate(Gf, 3, j0); n4 = ldgate(Gf, 4, j0); n5 = ldgate(Gf, 5, j0);
        n6 = ldgate(Gf, 6, j0);
    }

    float c = 0.f;
    float o0 = 0.f, o1 = 0.f, o2 = 0.f, o3 = 0.f, o4 = 0.f, o5 = 0.f, o6 = 0.f;
    float* outp = out + (size_t)b * NF;
    const bool isStore = (lay == 2) && (q == 0);

    for (int ep = 0; ep < NEP; ++ep) {
        const int k0 = ep * 7;
        float hh;

        __syncthreads();                       // drains prev epoch's loads/stores
        if (lay == 0) {
            u0 = n0; u1 = n1; u2 = n2; u3 = n3; u4 = n4; u5 = n5; u6 = n6;
            int tb = k0 + 7;
            n0 = ldgate(Gf, min(tb + 0, NF - 1), j0);
            n1 = ldgate(Gf, min(tb + 1, NF - 1), j0);
            n2 = ldgate(Gf, min(tb + 2, NF - 1), j0);
            n3 = ldgate(Gf, min(tb + 3, NF - 1), j0);
            n4 = ldgate(Gf, min(tb + 4, NF - 1), j0);
            n5 = ldgate(Gf, min(tb + 5, NF - 1), j0);
            n6 = ldgate(Gf, min(tb + 6, NF - 1), j0);
        }
        hh = step_fn(k0 + 0, u0, lay, lane, q, whh, wih, base, whr0, c, part4);
        if (isStore) o0 = hh;
        __syncthreads();
        hh = step_fn(k0 + 1, u1, lay, lane, q, whh, wih, base, whr0, c, part4);
        if (isStore) o1 = hh;
        __syncthreads();
        hh = step_fn(k0 + 2, u2, lay, lane, q, whh, wih, base, whr0, c, part4);
        if (isStore) o2 = hh;
        __syncthreads();
        hh = step_fn(k0 + 3, u3, lay, lane, q, whh, wih, base, whr0, c, part4);
        if (isStore) o3 = hh;
        __syncthreads();
        hh = step_fn(k0 + 4, u4, lay, lane, q, whh, wih, base, whr0, c, part4);
        if (isStore) o4 = hh;
        __syncthreads();
        hh = step_fn(k0 + 5, u5, lay, lane, q, whh, wih, base, whr0, c, part4);
        if (isStore) o5 = hh;
        __syncthreads();
        hh = step_fn(k0 + 6, u6, lay, lane, q, whh, wih, base, whr0, c, part4);
        if (isStore) o6 = hh;

        // h captured at step k is h(t = k-3); store the epoch's 7 values.
        if (isStore && lane == 0) {
            const int tb = k0 - 3;
            if ((unsigned)(tb + 0) < NF) outp[tb + 0] = o0;
            if ((unsigned)(tb + 1) < NF) outp[tb + 1] = o1;
            if ((unsigned)(tb + 2) < NF) outp[tb + 2] = o2;
            if ((unsigned)(tb + 3) < NF) outp[tb + 3] = o3;
            if ((unsigned)(tb + 4) < NF) outp[tb + 4] = o4;
            if ((unsigned)(tb + 5) < NF) outp[tb + 5] = o5;
            if ((unsigned)(tb + 6) < NF) outp[tb + 6] = o6;
        }
    }
}

// ---------------------------------------------------------------------------
extern "C" void kernel_launch(void* const* d_in, const int* in_sizes, int n_in,
                              void* d_out, int out_size, void* d_ws, size_t ws_size,
                              hipStream_t stream)
{
    const float* x    = (const float*)d_in[0];
    const float* f    = (const float*)d_in[1];
    const float* Wih0 = (const float*)d_in[2];
    const float* Whh0 = (const float*)d_in[3];
    const float* bih0 = (const float*)d_in[4];
    const float* bhh0 = (const float*)d_in[5];
    const float* Whr0 = (const float*)d_in[6];
    const float* Wih1 = (const float*)d_in[7];
    const float* Whh1 = (const float*)d_in[8];
    const float* bih1 = (const float*)d_in[9];
    const float* bhh1 = (const float*)d_in[10];
    const float* Whr1 = (const float*)d_in[11];
    const float* Wih2 = (const float*)d_in[12];
    const float* Whh2 = (const float*)d_in[13];
    const float* bih2 = (const float*)d_in[14];
    const float* bhh2 = (const float*)d_in[15];
    const float* Whr2 = (const float*)d_in[16];
    float* out = (float*)d_out;

    float* Gf  = (float*)d_ws;                       // NF * 1024 floats (4.1 MB)
    float* Gxb = Gf + (size_t)NF * 1024;             // 64 * 1024 floats

    gf_kernel<<<143, 1024, 0, stream>>>(f, Wih0, Gf);
    gxb_kernel<<<64, 1024, 0, stream>>>(x, Wih0, bih0, bhh0, Gxb);
    lstm_pipeline<<<B_DIM, 768, 0, stream>>>(Gf, Gxb, Whh0, Whr0,
                                             Wih1, Whh1, bih1, bhh1, Whr1,
                                             Wih2, Whh2, bih2, bhh2, Whr2,
                                             out);
}

// Round 9
// 487.547 us; speedup vs baseline: 1.9328x; 1.1159x over previous
//
#include <hip/hip_runtime.h>

// Problem dims
#define B_DIM 64
#define IN_CH 16
#define H_DIM 256
#define FDIM  128
#define NF    1001
#define INS0  144      // FDIM + IN_CH
#define TB    7        // timesteps per block in prep gf-role (1001 = 7*143)
#define U     7        // timesteps per pipeline epoch (1001 = 7*143, exact)
#define NEPOCH 143
#define GF_BLOCKS 143

// Gate pre-activations are PRE-SCALED so they feed v_exp_f32 (exp2) directly:
//   rows i,f,o:  scale = -log2(e)    -> exp2(arg) = e^{-gate}
//   row  g:      scale = -2*log2(e)  -> exp2(arg) = e^{-2*gate}
#define SC_IFO (-1.44269504088896340736f)
#define SC_G   (-2.88539008177792681472f)

__device__ __forceinline__ float gate_scale(int j) {
    return (j >= 512 && j < 768) ? SC_G : SC_IFO;
}

// ---------------------------------------------------------------------------
// Wave64 sum-reduce via DPP (VALU-rate). Result broadcast via readlane 63.
// ---------------------------------------------------------------------------
template<int CTRL, int ROW_MASK>
__device__ __forceinline__ float dpp_add(float x) {
    int y = __builtin_amdgcn_update_dpp(0, __float_as_int(x), CTRL, ROW_MASK, 0xf, true);
    return x + __int_as_float(y);
}
__device__ __forceinline__ float wave_allreduce(float x) {
    x = dpp_add<0x111, 0xf>(x);   // row_shr:1
    x = dpp_add<0x112, 0xf>(x);   // row_shr:2
    x = dpp_add<0x114, 0xf>(x);   // row_shr:4
    x = dpp_add<0x118, 0xf>(x);   // row_shr:8
    x = dpp_add<0x142, 0xa>(x);   // row_bcast:15 into rows 1,3
    x = dpp_add<0x143, 0xc>(x);   // row_bcast:31 into rows 2,3
    return __int_as_float(__builtin_amdgcn_readlane(__float_as_int(x), 63));
}

// ---------------------------------------------------------------------------
// Merged prep kernel. Blocks [0,143): Gf[t][j] = (f[t]·Wih0[j][:128])*scale(j)
// for the 7 timesteps of this block. Blocks [143,207): Gxb[b][j] =
// (x[b]·Wih0[j][128:] + bih0[j] + bhh0[j])*scale(j) for batch b = blk-143.
// One launch instead of two; the two roles are independent.
// ---------------------------------------------------------------------------
__global__ __launch_bounds__(1024) void prep_kernel(
    const float* __restrict__ f, const float* __restrict__ x,
    const float* __restrict__ W,
    const float* __restrict__ bih, const float* __restrict__ bhh,
    float* __restrict__ Gf, float* __restrict__ Gxb)
{
    const int tid = threadIdx.x;
    const int j = tid;
    if (blockIdx.x < GF_BLOCKS) {
        __shared__ float fs[TB][FDIM];
        const int t0 = blockIdx.x * TB;
        for (int i = tid; i < TB * FDIM; i += 1024)
            fs[i >> 7][i & 127] = f[t0 * FDIM + i];
        __syncthreads();

        const float4* w4 = (const float4*)(W + j * INS0);
        float acc[TB];
#pragma unroll
        for (int t = 0; t < TB; ++t) acc[t] = 0.f;
#pragma unroll
        for (int kc = 0; kc < 8; ++kc) {
            float4 a = w4[kc * 4 + 0];
            float4 b = w4[kc * 4 + 1];
            float4 c = w4[kc * 4 + 2];
            float4 d = w4[kc * 4 + 3];
#pragma unroll
            for (int t = 0; t < TB; ++t) {
                const float* fp = &fs[t][kc * 16];
                float s = acc[t];
                s = fmaf(a.x, fp[0], s);  s = fmaf(a.y, fp[1], s);
                s = fmaf(a.z, fp[2], s);  s = fmaf(a.w, fp[3], s);
                s = fmaf(b.x, fp[4], s);  s = fmaf(b.y, fp[5], s);
                s = fmaf(b.z, fp[6], s);  s = fmaf(b.w, fp[7], s);
                s = fmaf(c.x, fp[8], s);  s = fmaf(c.y, fp[9], s);
                s = fmaf(c.z, fp[10], s); s = fmaf(c.w, fp[11], s);
                s = fmaf(d.x, fp[12], s); s = fmaf(d.y, fp[13], s);
                s = fmaf(d.z, fp[14], s); s = fmaf(d.w, fp[15], s);
                acc[t] = s;
            }
        }
        const float sc = gate_scale(j);
#pragma unroll
        for (int t = 0; t < TB; ++t)
            Gf[(size_t)(t0 + t) * 1024 + j] = acc[t] * sc;
    } else {
        const int b = blockIdx.x - GF_BLOCKS;
        const float* w = W + j * INS0 + FDIM;
        const float* xb = x + b * IN_CH;
        float s = bih[j] + bhh[j];
#pragma unroll
        for (int k = 0; k < IN_CH; ++k) s = fmaf(xb[k], w[k], s);
        Gxb[b * 1024 + j] = s * gate_scale(j);
    }
}

// ---------------------------------------------------------------------------
// Main recurrence, epoch-pipelined (the measured-best 391us structure,
// round-3 source verbatim). grid = 64 (block = batch), block = 192 (3 waves,
// wave l = layer l). Epoch e: wave l processes the U=7 timesteps of its
// epoch te = e - l, consuming the 7 h-values wave l-1 produced in epoch e-1
// (double-buffered LDS, ONE __syncthreads per epoch). Per-unit math:
// 5 exp + 2 rcp with shared reciprocals, gates pre-scaled for exp2.
// Issue-bound on the trans pipe: ~28 trans x ~25cy + ~110 VALU x 2cy
// = ~920 cy/step (measured; structural roofline for this decomposition).
// ---------------------------------------------------------------------------
__global__ __launch_bounds__(192) void lstm_pipeline(
    const float* __restrict__ Gf, const float* __restrict__ Gxb,
    const float* __restrict__ Whh0, const float* __restrict__ Whr0,
    const float* __restrict__ Wih1, const float* __restrict__ Whh1,
    const float* __restrict__ bih1, const float* __restrict__ bhh1,
    const float* __restrict__ Whr1,
    const float* __restrict__ Wih2, const float* __restrict__ Whh2,
    const float* __restrict__ bih2, const float* __restrict__ bhh2,
    const float* __restrict__ Whr2,
    float* __restrict__ out)
{
    const int b    = blockIdx.x;
    const int wave = threadIdx.x >> 6;
    const int lane = threadIdx.x & 63;
    const int jb   = lane * 4;

    __shared__ float hbuf[3][2][U];   // [layer][parity][step-in-epoch]

    float base[16];   // wave0: Gxb (pre-scaled); wave1/2: (bih+bhh)*scale
    float wih[16];    // wave1/2: W_ih column * scale
    float whh[16];    // recurrent column * scale
    float whr[4];     // projection row slice (unscaled)

    const float *whh_p, *whr_p;
    if (wave == 0)      { whh_p = Whh0; whr_p = Whr0; }
    else if (wave == 1) { whh_p = Whh1; whr_p = Whr1; }
    else                { whh_p = Whh2; whr_p = Whr2; }

#pragma unroll
    for (int g = 0; g < 4; ++g) {
        const float sc = (g == 2) ? SC_G : SC_IFO;
        float4 w = *(const float4*)(whh_p + g * 256 + jb);
        whh[g*4+0] = w.x * sc; whh[g*4+1] = w.y * sc;
        whh[g*4+2] = w.z * sc; whh[g*4+3] = w.w * sc;
    }
    {
        float4 w = *(const float4*)(whr_p + jb);
        whr[0] = w.x; whr[1] = w.y; whr[2] = w.z; whr[3] = w.w;
    }

    if (wave == 0) {
#pragma unroll
        for (int g = 0; g < 4; ++g) {
            float4 v = *(const float4*)(Gxb + b * 1024 + g * 256 + jb);
            base[g*4+0] = v.x; base[g*4+1] = v.y; base[g*4+2] = v.z; base[g*4+3] = v.w;
            wih[g*4+0] = 0.f; wih[g*4+1] = 0.f; wih[g*4+2] = 0.f; wih[g*4+3] = 0.f;
        }
    } else {
        const float* bi = (wave == 1) ? bih1 : bih2;
        const float* bh = (wave == 1) ? bhh1 : bhh2;
        const float* wi = (wave == 1) ? Wih1 : Wih2;
#pragma unroll
        for (int g = 0; g < 4; ++g) {
            const float sc = (g == 2) ? SC_G : SC_IFO;
            float4 v1 = *(const float4*)(bi + g * 256 + jb);
            float4 v2 = *(const float4*)(bh + g * 256 + jb);
            float4 v3 = *(const float4*)(wi + g * 256 + jb);
            base[g*4+0] = (v1.x + v2.x) * sc; base[g*4+1] = (v1.y + v2.y) * sc;
            base[g*4+2] = (v1.z + v2.z) * sc; base[g*4+3] = (v1.w + v2.w) * sc;
            wih[g*4+0] = v3.x * sc; wih[g*4+1] = v3.y * sc;
            wih[g*4+2] = v3.z * sc; wih[g*4+3] = v3.w * sc;
        }
    }

    float c4[4] = {0.f, 0.f, 0.f, 0.f};
    float h_state = 0.f;

    for (int e = 0; e < NEPOCH + 2; ++e) {
        __syncthreads();
        const int te = e - wave;                  // this wave's epoch index
        const bool active = (te >= 0) && (te < NEPOCH);

        float pre[U][16];   // h-independent pre-scaled gate contribution

        if (active) {
            if (wave == 0) {
                const float* p = Gf + (size_t)te * U * 1024;
#pragma unroll
                for (int u = 0; u < U; ++u) {
#pragma unroll
                    for (int g = 0; g < 4; ++g) {
                        float4 v = *(const float4*)(p + u * 1024 + g * 256 + jb);
                        pre[u][g*4+0] = v.x + base[g*4+0];
                        pre[u][g*4+1] = v.y + base[g*4+1];
                        pre[u][g*4+2] = v.z + base[g*4+2];
                        pre[u][g*4+3] = v.w + base[g*4+3];
                    }
                }
            } else {
                const int par = (e - 1) & 1;
#pragma unroll
                for (int u = 0; u < U; ++u) {
                    float hin = hbuf[wave - 1][par][u];
#pragma unroll
                    for (int i = 0; i < 16; ++i)
                        pre[u][i] = fmaf(hin, wih[i], base[i]);
                }
            }

#pragma unroll
            for (int u = 0; u < U; ++u) {
                float m[4];
#pragma unroll
                for (int jj = 0; jj < 4; ++jj) {
                    float gi_s = fmaf(h_state, whh[0*4+jj], pre[u][0*4+jj]);
                    float gf_s = fmaf(h_state, whh[1*4+jj], pre[u][1*4+jj]);
                    float gg_s = fmaf(h_state, whh[2*4+jj], pre[u][2*4+jj]);
                    float go_s = fmaf(h_state, whh[3*4+jj], pre[u][3*4+jj]);
                    float A  = __builtin_amdgcn_exp2f(gi_s);   // e^-gi
                    float Dv = __builtin_amdgcn_exp2f(gf_s);   // e^-gf
                    float Bv = __builtin_amdgcn_exp2f(gg_s);   // e^-2gg
                    float Fv = __builtin_amdgcn_exp2f(go_s);   // e^-go
                    float a1 = 1.f + A, b1 = 1.f + Bv, d1 = 1.f + Dv, f1 = 1.f + Fv;
                    float p1 = a1 * b1;
                    float r1 = __builtin_amdgcn_rcpf(p1 * d1);
                    float si_tg = (1.f - Bv) * d1 * r1;        // sigmoid(gi)*tanh(gg)
                    float sf    = p1 * r1;                     // sigmoid(gf)
                    float c  = fmaf(sf, c4[jj], si_tg);
                    c4[jj] = c;
                    float Cv = __builtin_amdgcn_exp2f(SC_G * c);  // e^-2c
                    float r2 = __builtin_amdgcn_rcpf(f1 * (1.f + Cv));
                    float hr = (1.f - Cv) * r2;                // sigmoid(go)*tanh(c)
                    m[jj] = hr * whr[jj];
                }
                float contrib = (m[0] + m[1]) + (m[2] + m[3]);
                float tot = wave_allreduce(contrib);
                h_state = tot;
                if (lane == 0) hbuf[wave][e & 1][u] = tot;
                if (wave == 2 && lane == 0)
                    out[(size_t)b * NF + te * U + u] = tot;
            }
        }
    }
}

// ---------------------------------------------------------------------------
extern "C" void kernel_launch(void* const* d_in, const int* in_sizes, int n_in,
                              void* d_out, int out_size, void* d_ws, size_t ws_size,
                              hipStream_t stream)
{
    const float* x    = (const float*)d_in[0];
    const float* f    = (const float*)d_in[1];
    const float* Wih0 = (const float*)d_in[2];
    const float* Whh0 = (const float*)d_in[3];
    const float* bih0 = (const float*)d_in[4];
    const float* bhh0 = (const float*)d_in[5];
    const float* Whr0 = (const float*)d_in[6];
    const float* Wih1 = (const float*)d_in[7];
    const float* Whh1 = (const float*)d_in[8];
    const float* bih1 = (const float*)d_in[9];
    const float* bhh1 = (const float*)d_in[10];
    const float* Whr1 = (const float*)d_in[11];
    const float* Wih2 = (const float*)d_in[12];
    const float* Whh2 = (const float*)d_in[13];
    const float* bih2 = (const float*)d_in[14];
    const float* bhh2 = (const float*)d_in[15];
    const float* Whr2 = (const float*)d_in[16];
    float* out = (float*)d_out;

    float* Gf  = (float*)d_ws;                       // NF * 1024 floats (4.1 MB)
    float* Gxb = Gf + (size_t)NF * 1024;             // 64 * 1024 floats

    prep_kernel<<<GF_BLOCKS + B_DIM, 1024, 0, stream>>>(f, x, Wih0, bih0, bhh0,
                                                        Gf, Gxb);
    lstm_pipeline<<<B_DIM, 192, 0, stream>>>(Gf, Gxb, Whh0, Whr0,
                                             Wih1, Whh1, bih1, bhh1, Whr1,
                                             Wih2, Whh2, bih2, bhh2, Whr2,
                                             out);
}